// Round 8
// baseline (140.925 us; speedup 1.0000x reference)
//
#include <hip/hip_runtime.h>
#include <stdint.h>

// CropConv implicit GEMM (bf16 MFMA, fp32 accum).
//   M=64 (oc), K=576 (ic*3*3), N=262144 (b*h*w)
// v7: software pipeline. v6 post-mortem: A-hoist defeated by compiler
// (VGPR=108 < 144 needed -> loads re-sunk into K-loop); all v1-v6 share the
// 2-phase stage->drain-barrier->compute shape = ~5.5us/tile exposed latency.
//   - persistent blocks: grid 512 (= exactly 2 blocks/CU, no tail), each
//     processes T=4 consecutive output rows of one batch.
//   - 4-row LDS ring buffer (4 x 130cols x 64ic bf16 = 65 KiB, 2 blocks/CU):
//     consecutive tiles share 2 of 3 input rows -> stage ONE new row/tile.
//   - per tile: barrier -> ISSUE next-row loads (8 f32x4) -> sched_barrier(0)
//     (pins issue before K-loop; vmcnt-wait lands at the pack after ~2k cyc
//     of MFMA -> HBM latency hidden) -> K-loop (pure ds_read+MFMA, A in regs)
//     -> pack+ds_write ring slot (ht+3)&3 (disjoint from the 3 read slots;
//     one barrier/tile race-free) -> epilogue stores.
//   - A-loads outside the runtime tile loop -> loop-invariant, LICM-hoisted,
//     compiler cannot re-sink (would re-execute per iteration). 144 VGPR held.
//   - staging: j=t&7 octet-fastest lane map (v6's 0-conflict layout),
//     swizzle slot=(j+c)&7 unchanged.
// Weights: pre-pass -> bf16 workspace [kk][ch][i][lane] (72 KiB).
// Fallback: if ws_size < 73728, launch the v1 fully-fused kernel.

#define B_ 16
#define C_ 64
#define H_ 128
#define W_ 128

#define TCOLS_A 130
#define ROWU4   (TCOLS_A * 8)        // 1040 uint4 per ring row
#define XLDS_R  (4 * ROWU4)          // 4160 uint4 = 65 KiB
#define T_TILES 4

typedef float f32x4 __attribute__((ext_vector_type(4)));
typedef short bf16x8 __attribute__((ext_vector_type(8)));

__device__ inline unsigned short f2bf(float f) {
    union { float f; uint32_t u; } v; v.f = f;
    uint32_t u = v.u + 0x7FFF + ((v.u >> 16) & 1);   // RNE
    return (unsigned short)(u >> 16);
}

// ---- pre-pass: weights [oc][ic][3][3] fp32 -> bf16 [kk][ch][i][lane][e] ----
// element L = (((kk*2+ch)*4 + i)*64 + lane)*8 + e  holds
//   wgt[oc = i*16 + (lane&15)][ic = ch*32 + (lane>>4)*8 + e][kk]
__global__ __launch_bounds__(256) void xform_weight(
    const float* __restrict__ wgt, uint16_t* __restrict__ Wb)
{
    int L = blockIdx.x * 256 + threadIdx.x;       // < 36864
    int e    = L & 7;
    int lane = (L >> 3) & 63;
    int i    = (L >> 9) & 3;
    int ch   = (L >> 11) & 1;
    int kk   = L >> 12;
    int oc   = i * 16 + (lane & 15);
    int ic   = ch * 32 + (lane >> 4) * 8 + e;
    Wb[L] = f2bf(wgt[((size_t)oc * 64 + ic) * 9 + kk]);
}

// stage padded row p (input h = p-1) into ring slot p&3, immediately.
__device__ __forceinline__ void stage_row_now(
    uint4* lds, const float* __restrict__ xb, int p, int t)
{
    const int j     = t & 7;                  // ic octet (lane-fastest)
    const int c4    = t >> 3;                 // col-quad 0..31
    const int cbase = 1 + c4 * 4;
    const int wg0   = c4 * 4;
    const int sb    = (p & 3) * ROWU4;
    const int h     = p - 1;
    if (h < 0 || h >= H_) {
        uint4 z; z.x = z.y = z.z = z.w = 0;
        #pragma unroll
        for (int cc = 0; cc < 4; ++cc)
            lds[sb + (cbase + cc) * 8 + ((j + cbase + cc) & 7)] = z;
    } else {
        const float* src = xb + ((size_t)(j * 8) * H_ + h) * W_ + wg0;
        f32x4 f[8];
        #pragma unroll
        for (int e = 0; e < 8; ++e)
            f[e] = *(const f32x4*)(src + (size_t)e * (H_ * W_));
        #pragma unroll
        for (int cc = 0; cc < 4; ++cc) {
            uint32_t u[4];
            #pragma unroll
            for (int pp = 0; pp < 4; ++pp)
                u[pp] = (uint32_t)f2bf(f[2 * pp][cc]) |
                        ((uint32_t)f2bf(f[2 * pp + 1][cc]) << 16);
            lds[sb + (cbase + cc) * 8 + ((j + cbase + cc) & 7)] =
                *(const uint4*)u;
        }
    }
    if (t < 16) {                             // pad cols 0 and 129
        const int ce = (t < 8) ? 0 : (TCOLS_A - 1);
        const int jj = t & 7;
        uint4 z; z.x = z.y = z.z = z.w = 0;
        lds[sb + ce * 8 + ((jj + ce) & 7)] = z;
    }
}

// ---- main: persistent 4-tile block, 4-row ring, pipelined staging ----
// grid 512 = 16 b x 32 h-groups; block 256 = 4 waves;
// wave wv: ohalf = wv&1 (oc 32*ohalf..+31), whalf = wv>>1 (w 64*whalf..+63).
__global__ __launch_bounds__(256, 2) void conv_main(
    const uint4* __restrict__ Wq,    // [9][2][4][64] uint4 bf16
    const float* __restrict__ x,     // [16][64][128][128] fp32
    float* __restrict__ out)         // [16][64][128][128] fp32
{
    __shared__ uint4 lds[XLDS_R];    // 65 KiB

    const int t    = threadIdx.x;
    const int lane = t & 63;
    const int wv   = t >> 6;
    const int n    = lane & 15;
    const int q    = lane >> 4;

    // XCD-contiguous remap (512 = 8 * 64, bijective): consecutive h-groups
    // of one batch land on the same XCD -> halo rows L2-hot.
    const int d    = blockIdx.x;
    const int orig = (d & 7) * 64 + (d >> 3);
    const int hg   = orig & 31;
    const int b    = orig >> 5;
    const int h0   = hg * 4;                  // first output row of this block

    const int ohalf = wv & 1;
    const int wq    = (wv >> 1) * 64;

    const float* xb = x + (size_t)b * C_ * H_ * W_;

    // ---- A-hoist: 36 fragments (144 VGPR), loop-invariant across tiles ----
    bf16x8 Areg[18][2];
    #pragma unroll
    for (int g = 0; g < 18; ++g)
        #pragma unroll
        for (int i = 0; i < 2; ++i)
            Areg[g][i] = __builtin_bit_cast(bf16x8,
                Wq[(g * 4 + ohalf * 2 + i) * 64 + lane]);

    // ---- prologue: stage padded rows h0, h0+1, h0+2 ----
    #pragma unroll
    for (int r = 0; r < 3; ++r)
        stage_row_now(lds, xb, h0 + r, t);

    // staging thread mapping (pipelined path)
    const int sj    = t & 7;
    const int sc4   = t >> 3;
    const int scb   = 1 + sc4 * 4;
    const int swg0  = sc4 * 4;

    #pragma unroll 1
    for (int it = 0; it < T_TILES; ++it) {
        const int ht = h0 + it;
        __syncthreads();

        // ---- issue next-row loads (row p = ht+3, slot (ht+3)&3) ----
        const int  pnext = ht + 3;
        const bool dopf  = (it < T_TILES - 1);
        const bool zrow  = (pnext - 1 >= H_);     // p == 129 only
        f32x4 pf[8];
        if (dopf && !zrow) {
            const float* src =
                xb + ((size_t)(sj * 8) * H_ + (pnext - 1)) * W_ + swg0;
            #pragma unroll
            for (int e = 0; e < 8; ++e)
                pf[e] = *(const f32x4*)(src + (size_t)e * (H_ * W_));
        }
        __builtin_amdgcn_sched_barrier(0);   // pin issue before K-loop

        // ---- K-loop: 18 groups, pure ds_read_b128 + MFMA, A from regs ----
        f32x4 acc[2][4];
        #pragma unroll
        for (int i = 0; i < 2; ++i)
            #pragma unroll
            for (int f = 0; f < 4; ++f)
                acc[i][f] = (f32x4){0.f, 0.f, 0.f, 0.f};

        const int sbs[3] = { (ht & 3) * ROWU4,
                             ((ht + 1) & 3) * ROWU4,
                             ((ht + 2) & 3) * ROWU4 };

        #pragma unroll
        for (int kh = 0; kh < 3; ++kh) {
            #pragma unroll
            for (int kw = 0; kw < 3; ++kw) {
                #pragma unroll
                for (int ch = 0; ch < 2; ++ch) {
                    const int g = (kh * 3 + kw) * 2 + ch;
                    bf16x8 bb[4];
                    #pragma unroll
                    for (int f = 0; f < 4; ++f) {
                        const int ct  = wq + f * 16 + n + kw;   // 0..129
                        const int idx = sbs[kh] + ct * 8 +
                                        ((ch * 4 + q + ct) & 7);
                        bb[f] = __builtin_bit_cast(bf16x8, lds[idx]);
                    }
                    #pragma unroll
                    for (int i = 0; i < 2; ++i)
                        #pragma unroll
                        for (int f = 0; f < 4; ++f)
                            acc[i][f] = __builtin_amdgcn_mfma_f32_16x16x32_bf16(
                                Areg[g][i], bb[f], acc[i][f], 0, 0, 0);
                }
            }
        }

        // ---- pack + ds_write prefetched row (write-late) ----
        if (dopf) {
            const int sb = (pnext & 3) * ROWU4;
            if (!zrow) {
                #pragma unroll
                for (int cc = 0; cc < 4; ++cc) {
                    uint32_t u[4];
                    #pragma unroll
                    for (int pp = 0; pp < 4; ++pp)
                        u[pp] = (uint32_t)f2bf(pf[2 * pp][cc]) |
                                ((uint32_t)f2bf(pf[2 * pp + 1][cc]) << 16);
                    lds[sb + (scb + cc) * 8 + ((sj + scb + cc) & 7)] =
                        *(const uint4*)u;
                }
            } else {
                uint4 z; z.x = z.y = z.z = z.w = 0;
                #pragma unroll
                for (int cc = 0; cc < 4; ++cc)
                    lds[sb + (scb + cc) * 8 + ((sj + scb + cc) & 7)] = z;
            }
            if (t < 16) {
                const int ce = (t < 8) ? 0 : (TCOLS_A - 1);
                const int jj = t & 7;
                uint4 z; z.x = z.y = z.z = z.w = 0;
                lds[sb + ce * 8 + ((jj + ce) & 7)] = z;
            }
        }

        // ---- epilogue: oc = ohalf*32 + i*16 + q*4 + r, crop mask ----
        const bool hz = (ht >= 44 && ht < 84);
        #pragma unroll
        for (int f = 0; f < 4; ++f) {
            const int w0 = wq + f * 16 + n;
            const bool zz = hz && (w0 >= 44 && w0 < 84);
            #pragma unroll
            for (int i = 0; i < 2; ++i) {
                #pragma unroll
                for (int r = 0; r < 4; ++r) {
                    const int oc = ohalf * 32 + i * 16 + q * 4 + r;
                    out[(((size_t)b * C_ + oc) * H_ + ht) * W_ + w0] =
                        zz ? 0.f : acc[i][f][r];
                }
            }
        }
    }
}

// ================= fallback: fully-fused single kernel (v1, 88.5 us) ========
#define WLDS_U4 4608   // 9*2*4*64 uint4 = 72 KiB weights
#define FXLDS_U4 4096  // 4*128*8 uint4 = 64 KiB input tile

__global__ __launch_bounds__(256, 1) void conv_fused(
    const float* __restrict__ x,
    const float* __restrict__ wgt,
    float* __restrict__ out)
{
    __shared__ uint4 lds[WLDS_U4 + FXLDS_U4];          // 136 KiB
    uint16_t* lds16 = (uint16_t*)lds;

    const int t    = threadIdx.x;
    const int lane = t & 63;
    const int wv   = t >> 6;
    const int n    = lane & 15;
    const int q    = lane >> 4;

    const int d    = blockIdx.x;
    const int orig = (d & 7) * 128 + (d >> 3);
    const int b    = orig >> 6;
    const int h0   = (orig & 63) * 2;

    #pragma unroll
    for (int p = 0; p < 2; ++p) {
        const int a_  = t + 256 * p;
        const int oc  = a_ >> 3;
        const int oct = a_ & 7;
        const float* src = wgt + (size_t)oc * 576 + (size_t)oct * 72;
        f32x4 w4[18];
        #pragma unroll
        for (int j = 0; j < 18; ++j) w4[j] = ((const f32x4*)src)[j];
        const int ch = oct >> 2, qq = oct & 3;
        const int ii = oc >> 4,  nn = oc & 15;
        #pragma unroll
        for (int kk = 0; kk < 9; ++kk) {
            #define WELEM(e) ((uint32_t)f2bf(w4[((e)*9 + kk) >> 2][((e)*9 + kk) & 3]))
            uint4 val;
            val.x = WELEM(0) | (WELEM(1) << 16);
            val.y = WELEM(2) | (WELEM(3) << 16);
            val.z = WELEM(4) | (WELEM(5) << 16);
            val.w = WELEM(6) | (WELEM(7) << 16);
            #undef WELEM
            lds[((kk * 2 + ch) * 4 + ii) * 64 + qq * 16 + nn] = val;
        }
    }

    {
        const int ic    = t >> 2;
        const int w0    = (t & 3) * 32;
        const int jslot = ic >> 3;
        const int esub  = ic & 7;
        #pragma unroll
        for (int r = 0; r < 4; ++r) {
            const int h = h0 - 1 + r;
            if (h < 0 || h >= H_) {
                uint4 z; z.x = z.y = z.z = z.w = 0;
                #pragma unroll
                for (int k = 0; k < 4; ++k)
                    lds[WLDS_U4 + r * 1024 + k * 256 + t] = z;
            } else {
                const float* src =
                    x + (((size_t)(b * C_ + ic)) * H_ + h) * W_ + w0;
                f32x4 v4[8];
                #pragma unroll
                for (int j = 0; j < 8; ++j) v4[j] = ((const f32x4*)src)[j];
                #pragma unroll
                for (int k = 0; k < 32; ++k) {
                    const int c    = w0 + k;
                    const int slot = (jslot + c) & 7;
                    lds16[WLDS_U4 * 8 + ((r * 128 + c) * 8 + slot) * 8 + esub] =
                        f2bf(v4[k >> 2][k & 3]);
                }
            }
        }
    }
    __syncthreads();

    f32x4 acc[4][4];
    #pragma unroll
    for (int i = 0; i < 4; ++i)
        #pragma unroll
        for (int tt = 0; tt < 4; ++tt)
            acc[i][tt] = (f32x4){0.f, 0.f, 0.f, 0.f};

    const int wb = (wv & 1) * 64;
    const uint4* Wl = lds;
    const uint4* Xl = lds + WLDS_U4;
    const bool lz = (wb + n) == 0;
    const bool rz = (wb + n) == 79;
    const bf16x8 zfrag = 0;

    #pragma unroll
    for (int kh = 0; kh < 3; ++kh) {
        const int row = (wv >> 1) + kh;
        #pragma unroll
        for (int kw = 0; kw < 3; ++kw) {
            const int kk = kh * 3 + kw;
            #pragma unroll
            for (int ch = 0; ch < 2; ++ch) {
                bf16x8 a[4], bb[4];
                #pragma unroll
                for (int i = 0; i < 4; ++i)
                    a[i] = __builtin_bit_cast(bf16x8,
                        Wl[((kk * 2 + ch) * 4 + i) * 64 + lane]);
                #pragma unroll
                for (int tt = 0; tt < 4; ++tt) {
                    int c   = wb + tt * 16 + n + kw - 1;
                    int cc  = min(max(c, 0), 127);
                    int idx = (row * 128 + cc) * 8 + ((ch * 4 + q + cc) & 7);
                    bf16x8 v = __builtin_bit_cast(bf16x8, Xl[idx]);
                    if (kw == 0 && tt == 0) v = lz ? zfrag : v;
                    if (kw == 2 && tt == 3) v = rz ? zfrag : v;
                    bb[tt] = v;
                }
                #pragma unroll
                for (int i = 0; i < 4; ++i)
                    #pragma unroll
                    for (int tt = 0; tt < 4; ++tt)
                        acc[i][tt] = __builtin_amdgcn_mfma_f32_16x16x32_bf16(
                            a[i], bb[tt], acc[i][tt], 0, 0, 0);
            }
        }
    }

    const int  h  = h0 + (wv >> 1);
    const bool hz = (h >= 44 && h < 84);
    #pragma unroll
    for (int i = 0; i < 4; ++i) {
        #pragma unroll
        for (int tt = 0; tt < 4; ++tt) {
            const int  w0 = wb + tt * 16 + n;
            const bool zz = hz && (w0 >= 44 && w0 < 84);
            #pragma unroll
            for (int r = 0; r < 4; ++r) {
                const int oc = i * 16 + q * 4 + r;
                out[(((size_t)b * C_ + oc) * H_ + h) * W_ + w0] =
                    zz ? 0.f : acc[i][tt][r];
            }
        }
    }
}

extern "C" void kernel_launch(void* const* d_in, const int* in_sizes, int n_in,
                              void* d_out, int out_size, void* d_ws, size_t ws_size,
                              hipStream_t stream) {
    const float* x   = (const float*)d_in[0];
    const float* wgt = (const float*)d_in[1];
    float* out       = (float*)d_out;

    const size_t W_BYTES = 9 * 2 * 4 * 64 * 16;   // 73,728
    if (ws_size >= W_BYTES) {
        uint16_t* Wb = (uint16_t*)d_ws;
        xform_weight<<<dim3(144), dim3(256), 0, stream>>>(wgt, Wb);
        conv_main<<<dim3(512), dim3(256), 0, stream>>>(
            (const uint4*)Wb, x, out);
    } else {
        conv_fused<<<dim3(1024), dim3(256), 0, stream>>>(x, wgt, out);
    }
}